// Round 7
// baseline (326.749 us; speedup 1.0000x reference)
//
#include <hip/hip_runtime.h>

#define N_NODES 50000
#define N_EDGES 800000

static inline size_t align256(size_t x) { return (x + 255) & ~(size_t)255; }

typedef _Float16 f16x8 __attribute__((ext_vector_type(8)));   // 8 fp16 in 4 VGPRs
typedef _Float16 f16x4 __attribute__((ext_vector_type(4)));
typedef float f32x4 __attribute__((ext_vector_type(4)));

// ---------------- CSR build ----------------

// rank[e] = position of edge e within its destination's bucket
__global__ void count_kernel(const int* __restrict__ dst, int* __restrict__ counts,
                             int* __restrict__ rank, int E) {
    int e = blockIdx.x * blockDim.x + threadIdx.x;
    if (e < E) rank[e] = atomicAdd(&counts[dst[e]], 1);
}

__global__ void scan1_kernel(const int* __restrict__ counts, int* __restrict__ row_ptr,
                             int* __restrict__ bsum, int n) {
    __shared__ int sd[1024];
    int i = blockIdx.x * 1024 + threadIdx.x;
    int v = (i < n) ? counts[i] : 0;
    sd[threadIdx.x] = v;
    __syncthreads();
    #pragma unroll
    for (int off = 1; off < 1024; off <<= 1) {
        int t = 0;
        if ((int)threadIdx.x >= off) t = sd[threadIdx.x - off];
        __syncthreads();
        sd[threadIdx.x] += t;
        __syncthreads();
    }
    if (i < n) row_ptr[i + 1] = sd[threadIdx.x];
    if (threadIdx.x == 1023) bsum[blockIdx.x] = sd[1023];
}

__global__ void scan2_kernel(int* __restrict__ bsum, int nb) {
    if (threadIdx.x == 0) {
        int acc = 0;
        for (int b = 0; b < nb; ++b) { int t = bsum[b]; bsum[b] = acc; acc += t; }
    }
}

__global__ void scan3_kernel(int* __restrict__ row_ptr, const int* __restrict__ bsum,
                             const int* __restrict__ counts, float* __restrict__ dis, int n) {
    int i = blockIdx.x * blockDim.x + threadIdx.x;
    if (i < n) {
        row_ptr[i + 1] += bsum[i >> 10];
        dis[i] = rsqrtf((float)(counts[i] + 1));
        if (i == 0) row_ptr[0] = 0;
    }
}

// no atomic: slot is row_ptr[dst] + rank  (store is fire-and-forget)
__global__ void fill_kernel(const int* __restrict__ src, const int* __restrict__ dst,
                            const int* __restrict__ rank, const int* __restrict__ row_ptr,
                            int* __restrict__ col, int E) {
    int e = blockIdx.x * blockDim.x + threadIdx.x;
    if (e < E) col[row_ptr[dst[e]] + rank[e]] = src[e];
}

// xs_h[v,:] = fp16(dis[v] * x[v,:])   (D = 128; one half4 per thread)
__global__ void xs_half_kernel(const float* __restrict__ x, const float* __restrict__ dis,
                               _Float16* __restrict__ xs, int nq) {
    int q = blockIdx.x * blockDim.x + threadIdx.x;
    if (q < nq) {
        int v = q >> 5;                      // 32 quads per row
        float s = dis[v];
        float4 t = *(const float4*)(x + (size_t)q * 4);
        f16x4 h;
        h.x = (_Float16)(s * t.x); h.y = (_Float16)(s * t.y);
        h.z = (_Float16)(s * t.z); h.w = (_Float16)(s * t.w);
        ((f16x4*)xs)[q] = h;
    }
}

// ---------------- W packing: fragment-order hi/lo fp16 ----------------

__global__ void pack_w(const float* __restrict__ W, _Float16* __restrict__ Ph,
                       _Float16* __restrict__ Pl, int K, int N) {
    int id = blockIdx.x * blockDim.x + threadIdx.x;
    int total = (K >> 5) * (N >> 4) * 64;
    if (id >= total) return;
    int l = id & 63;
    int f = id >> 6;
    int nf16 = N >> 4;
    int ks = f / nf16, nf = f - ks * nf16;
    int k0 = ks * 32 + (l >> 4) * 8;
    int n  = nf * 16 + (l & 15);
    #pragma unroll
    for (int j = 0; j < 8; ++j) {
        float v = W[(size_t)(k0 + j) * N + n];
        _Float16 hi = (_Float16)v;
        Ph[(size_t)id * 8 + j] = hi;
        Pl[(size_t)id * 8 + j] = (_Float16)(v - (float)hi);
    }
}

// ---------------- MFMA GEMM (fp16 split x3): G = epi(A @ W) ----------------

template <int EPI, int K, int N>
__global__ __launch_bounds__(256) void mfma_gemm(
    const _Float16* __restrict__ Ah, const _Float16* __restrict__ Al,
    const _Float16* __restrict__ Bh, const _Float16* __restrict__ Bl,
    const float* __restrict__ dis, const float* __restrict__ bias,
    _Float16* __restrict__ G16, _Float16* __restrict__ Oh, _Float16* __restrict__ Ol,
    int M) {

    int t = threadIdx.x;
    int w = t >> 6, l = t & 63;
    int m0 = blockIdx.y * 128 + w * 32;
    int n0 = blockIdx.x * 64;

    int lrow = l & 15;
    int lk   = (l >> 4) * 8;

    int r0 = m0 + lrow, r1 = m0 + 16 + lrow;
    bool ok0 = r0 < M, ok1 = r1 < M;

    const _Float16* pAh0 = Ah + (size_t)r0 * K + lk;
    const _Float16* pAl0 = Al + (size_t)r0 * K + lk;
    const _Float16* pAh1 = Ah + (size_t)r1 * K + lk;
    const _Float16* pAl1 = Al + (size_t)r1 * K + lk;

    const int nf16 = N >> 4;
    const _Float16* pBh = Bh + (size_t)(n0 >> 4) * 512 + (size_t)l * 8;
    const _Float16* pBl = Bl + (size_t)(n0 >> 4) * 512 + (size_t)l * 8;

    f32x4 acc[2][4] = {};
    f16x8 z8 = {0, 0, 0, 0, 0, 0, 0, 0};

    #pragma unroll
    for (int kt = 0; kt < K; kt += 32) {
        f16x8 ah0 = ok0 ? *(const f16x8*)(pAh0 + kt) : z8;
        f16x8 al0 = ok0 ? *(const f16x8*)(pAl0 + kt) : z8;
        f16x8 ah1 = ok1 ? *(const f16x8*)(pAh1 + kt) : z8;
        f16x8 al1 = ok1 ? *(const f16x8*)(pAl1 + kt) : z8;

        const size_t boff = (size_t)(kt >> 5) * nf16 * 512;
        #pragma unroll
        for (int c = 0; c < 4; ++c) {
            f16x8 bh = *(const f16x8*)(pBh + boff + (size_t)c * 512);
            f16x8 bl = *(const f16x8*)(pBl + boff + (size_t)c * 512);
            acc[0][c] = __builtin_amdgcn_mfma_f32_16x16x32_f16(ah0, bh, acc[0][c], 0, 0, 0);
            acc[0][c] = __builtin_amdgcn_mfma_f32_16x16x32_f16(al0, bh, acc[0][c], 0, 0, 0);
            acc[0][c] = __builtin_amdgcn_mfma_f32_16x16x32_f16(ah0, bl, acc[0][c], 0, 0, 0);
            acc[1][c] = __builtin_amdgcn_mfma_f32_16x16x32_f16(ah1, bh, acc[1][c], 0, 0, 0);
            acc[1][c] = __builtin_amdgcn_mfma_f32_16x16x32_f16(al1, bh, acc[1][c], 0, 0, 0);
            acc[1][c] = __builtin_amdgcn_mfma_f32_16x16x32_f16(ah1, bl, acc[1][c], 0, 0, 0);
        }
    }

    float bvals[4];
    if (EPI == 1) {
        #pragma unroll
        for (int c = 0; c < 4; ++c) bvals[c] = bias[n0 + c * 16 + lrow];
    }

    #pragma unroll
    for (int rf = 0; rf < 2; ++rf) {
        int mb = m0 + rf * 16 + (l >> 4) * 4;
        #pragma unroll
        for (int r = 0; r < 4; ++r) {
            int m = mb + r;
            if (m < M) {
                if (EPI == 0) {
                    float s = dis[m];
                    #pragma unroll
                    for (int c = 0; c < 4; ++c) {
                        int n = n0 + c * 16 + lrow;
                        G16[(size_t)m * N + n] = (_Float16)(s * acc[rf][c][r]);
                    }
                } else {
                    #pragma unroll
                    for (int c = 0; c < 4; ++c) {
                        int n = n0 + c * 16 + lrow;
                        float v = fmaxf(acc[rf][c][r] + bvals[c], 0.f);
                        _Float16 hi = (_Float16)v;
                        Oh[(size_t)m * N + n] = hi;
                        Ol[(size_t)m * N + n] = (_Float16)(v - (float)hi);
                    }
                }
            }
        }
    }
}

// ---------------- Aggregation (fp16 gather, split-edge groups) ----------------
// DQ = D/4 column-quads; G edge-groups per node; TPN = DQ*G threads per node.
// Group q handles edges s+q, s+q+G, ... ; cross-group reduce via shfl_xor.
// MODE 0: out split(dis[v]*sum)             -> oh/ol fp16   (feeds GEMM)
// MODE 2: out fp16(dis*relu(dis*sum + b))   -> o16          (prescaled for next agg)
// MODE 3: out fp32(dis*sum + b)             -> outf         (final layer)

template <int MODE, int DQ, int G>
__global__ __launch_bounds__(256) void agg4(
    const _Float16* __restrict__ g, const int* __restrict__ row_ptr,
    const int* __restrict__ col, const float* __restrict__ dis,
    const float* __restrict__ bias, float* __restrict__ outf,
    _Float16* __restrict__ o16, _Float16* __restrict__ oh, _Float16* __restrict__ ol) {
    const int TPN = DQ * G;            // threads per node (<= 64)
    const int NPB = 256 / TPN;         // nodes per block
    int t = threadIdx.x;
    int nl = t / TPN;
    int r  = t % TPN;
    int c  = r % DQ;                   // column quad
    int q  = r / DQ;                   // edge group
    int v  = blockIdx.x * NPB + nl;
    const f16x4* g4 = (const f16x4*)g;
    size_t rowq = (size_t)v * DQ + c;

    float4 sum = make_float4(0.f, 0.f, 0.f, 0.f);
    if (q == 0) {                      // self-loop term (group 0 only)
        f16x4 sf = g4[rowq];
        sum = make_float4((float)sf.x, (float)sf.y, (float)sf.z, (float)sf.w);
    }

    int s = row_ptr[v], e = row_ptr[v + 1];
    int i = s + q;
    for (; i + 3 * G < e; i += 4 * G) {
        int u0 = col[i], u1 = col[i + G], u2 = col[i + 2 * G], u3 = col[i + 3 * G];
        f16x4 f0 = g4[(size_t)u0 * DQ + c];
        f16x4 f1 = g4[(size_t)u1 * DQ + c];
        f16x4 f2 = g4[(size_t)u2 * DQ + c];
        f16x4 f3 = g4[(size_t)u3 * DQ + c];
        sum.x += ((float)f0.x + (float)f1.x) + ((float)f2.x + (float)f3.x);
        sum.y += ((float)f0.y + (float)f1.y) + ((float)f2.y + (float)f3.y);
        sum.z += ((float)f0.z + (float)f1.z) + ((float)f2.z + (float)f3.z);
        sum.w += ((float)f0.w + (float)f1.w) + ((float)f2.w + (float)f3.w);
    }
    for (; i < e; i += G) {
        f16x4 f = g4[(size_t)col[i] * DQ + c];
        sum.x += (float)f.x; sum.y += (float)f.y;
        sum.z += (float)f.z; sum.w += (float)f.w;
    }

    // cross-group reduce (TPN <= 64 so all partners are within the wave)
    #pragma unroll
    for (int off = DQ; off < TPN; off <<= 1) {
        sum.x += __shfl_xor(sum.x, off);
        sum.y += __shfl_xor(sum.y, off);
        sum.z += __shfl_xor(sum.z, off);
        sum.w += __shfl_xor(sum.w, off);
    }
    if (q != 0) return;

    float dv = dis[v];
    if (MODE == 0) {
        float r0 = dv * sum.x, r1 = dv * sum.y, r2 = dv * sum.z, r3 = dv * sum.w;
        f16x4 h, lo;
        h.x = (_Float16)r0; lo.x = (_Float16)(r0 - (float)h.x);
        h.y = (_Float16)r1; lo.y = (_Float16)(r1 - (float)h.y);
        h.z = (_Float16)r2; lo.z = (_Float16)(r2 - (float)h.z);
        h.w = (_Float16)r3; lo.w = (_Float16)(r3 - (float)h.w);
        ((f16x4*)oh)[rowq] = h;
        ((f16x4*)ol)[rowq] = lo;
    } else {
        float4 b4 = ((const float4*)bias)[c];
        float r0 = dv * sum.x + b4.x, r1 = dv * sum.y + b4.y;
        float r2 = dv * sum.z + b4.z, r3 = dv * sum.w + b4.w;
        if (MODE == 2) {
            r0 = fmaxf(r0, 0.f) * dv; r1 = fmaxf(r1, 0.f) * dv;
            r2 = fmaxf(r2, 0.f) * dv; r3 = fmaxf(r3, 0.f) * dv;
            f16x4 h;
            h.x = (_Float16)r0; h.y = (_Float16)r1;
            h.z = (_Float16)r2; h.w = (_Float16)r3;
            ((f16x4*)o16)[rowq] = h;
        } else {
            ((float4*)outf)[rowq] = make_float4(r0, r1, r2, r3);
        }
    }
}

// ---------------- launch ----------------

extern "C" void kernel_launch(void* const* d_in, const int* in_sizes, int n_in,
                              void* d_out, int out_size, void* d_ws, size_t ws_size,
                              hipStream_t stream) {
    const int N = N_NODES, E = N_EDGES;

    const float* x   = (const float*)d_in[0];
    const int*   ei  = (const int*)d_in[1];
    const int*   src = ei;
    const int*   dst = ei + E;
    const float* W1 = (const float*)d_in[2];  const float* b1 = (const float*)d_in[3];
    const float* W2 = (const float*)d_in[4];  const float* b2 = (const float*)d_in[5];
    const float* W3 = (const float*)d_in[6];  const float* b3 = (const float*)d_in[7];
    const float* W4 = (const float*)d_in[8];  const float* b4 = (const float*)d_in[9];
    float* out = (float*)d_out;

    // workspace carve-up
    char* w = (char*)d_ws;
    int*   counts  = (int*)w;    w += align256((size_t)N * 4);
    int*   row_ptr = (int*)w;    w += align256((size_t)(N + 1) * 4);
    float* dis     = (float*)w;  w += align256((size_t)N * 4);
    int*   bsum    = (int*)w;    w += align256((size_t)64 * 4);
    int*   rank    = (int*)w;    w += align256((size_t)E * 4);
    int*   col     = (int*)w;    w += align256((size_t)E * 4);
    _Float16* w1h = (_Float16*)w; w += align256(32768 * 2);
    _Float16* w1l = (_Float16*)w; w += align256(32768 * 2);
    _Float16* w2h = (_Float16*)w; w += align256(16384 * 2);
    _Float16* w2l = (_Float16*)w; w += align256(16384 * 2);
    _Float16* w3h = (_Float16*)w; w += align256(16384 * 2);
    _Float16* w3l = (_Float16*)w; w += align256(16384 * 2);
    _Float16* w4h = (_Float16*)w; w += align256(32768 * 2);
    _Float16* w4l = (_Float16*)w; w += align256(32768 * 2);
    // arenas (aliased across phases), all fp16
    char* A1 = w;  w += align256((size_t)N * 128 * 2);   // xs | t3h+t3l
    char* A2 = w;  w += align256((size_t)N * 128 * 2);   // t1h | g2+h2s
    char* A3 = w;  w += align256((size_t)N * 128 * 2);   // t1l | gg4
    char* A4 = w;  w += align256((size_t)N * 256 * 2);   // h1h | h3h
    char* A5 = w;  w += align256((size_t)N * 256 * 2);   // h1l | h3l

    _Float16* xs  = (_Float16*)A1;
    _Float16* t1h = (_Float16*)A2;
    _Float16* t1l = (_Float16*)A3;
    _Float16* h1h = (_Float16*)A4;
    _Float16* h1l = (_Float16*)A5;
    _Float16* g2  = (_Float16*)A2;
    _Float16* h2s = (_Float16*)(A2 + (size_t)N * 64 * 2);
    _Float16* t3h = (_Float16*)A1;
    _Float16* t3l = (_Float16*)(A1 + (size_t)N * 64 * 2);
    _Float16* h3h = (_Float16*)A4;
    _Float16* h3l = (_Float16*)A5;
    _Float16* gg4 = (_Float16*)A3;

    // ---- CSR build ----
    const int nb = (N + 1023) / 1024;
    hipMemsetAsync(counts, 0, (size_t)N * 4, stream);
    count_kernel<<<(E + 255) / 256, 256, 0, stream>>>(dst, counts, rank, E);
    scan1_kernel<<<nb, 1024, 0, stream>>>(counts, row_ptr, bsum, N);
    scan2_kernel<<<1, 64, 0, stream>>>(bsum, nb);
    scan3_kernel<<<(N + 255) / 256, 256, 0, stream>>>(row_ptr, bsum, counts, dis, N);
    fill_kernel<<<(E + 255) / 256, 256, 0, stream>>>(src, dst, rank, row_ptr, col, E);

    // ---- pack weights ----
    pack_w<<<(4096 + 255) / 256, 256, 0, stream>>>(W1, w1h, w1l, 128, 256);
    pack_w<<<(2048 + 255) / 256, 256, 0, stream>>>(W2, w2h, w2l, 256, 64);
    pack_w<<<(2048 + 255) / 256, 256, 0, stream>>>(W3, w3h, w3l, 64, 256);
    pack_w<<<(4096 + 255) / 256, 256, 0, stream>>>(W4, w4h, w4l, 256, 128);

    const int gy = (N + 127) / 128;   // 391

    // ---- layer 1 (agg-first): xs = fp16(dis*x) ; t1 = Âs xs ; h1 = relu(t1 @ W1 + b1) ----
    xs_half_kernel<<<(N * 32 + 255) / 256, 256, 0, stream>>>(x, dis, xs, N * 32);
    agg4<0, 32, 2><<<N / 4, 256, 0, stream>>>(xs, row_ptr, col, dis, nullptr,
                                              nullptr, nullptr, t1h, t1l);
    mfma_gemm<1, 128, 256><<<dim3(4, gy), 256, 0, stream>>>(t1h, t1l, w1h, w1l, dis, b1,
                                                            nullptr, h1h, h1l, N);

    // ---- layer 2 (agg-after): g2 = fp16(dis*(h1 @ W2)) ; h2s = fp16(dis*relu(agg + b2)) ----
    mfma_gemm<0, 256, 64><<<dim3(1, gy), 256, 0, stream>>>(h1h, h1l, w2h, w2l, dis, b2,
                                                           g2, nullptr, nullptr, N);
    agg4<2, 16, 4><<<N / 4, 256, 0, stream>>>(g2, row_ptr, col, dis, b2,
                                              nullptr, h2s, nullptr, nullptr);

    // ---- layer 3 (agg-first): t3 = Âs h2s ; h3 = relu(t3 @ W3 + b3) ----
    agg4<0, 16, 4><<<N / 4, 256, 0, stream>>>(h2s, row_ptr, col, dis, nullptr,
                                              nullptr, nullptr, t3h, t3l);
    mfma_gemm<1, 64, 256><<<dim3(4, gy), 256, 0, stream>>>(t3h, t3l, w3h, w3l, dis, b3,
                                                           nullptr, h3h, h3l, N);

    // ---- layer 4 (agg-after): gg4 = fp16(dis*(h3 @ W4)) ; out = agg + b4 ----
    mfma_gemm<0, 256, 128><<<dim3(2, gy), 256, 0, stream>>>(h3h, h3l, w4h, w4l, dis, b4,
                                                            gg4, nullptr, nullptr, N);
    agg4<3, 32, 2><<<N / 4, 256, 0, stream>>>(gg4, row_ptr, col, dis, b4,
                                              out, nullptr, nullptr, nullptr);
}

// Round 8
// 310.834 us; speedup vs baseline: 1.0512x; 1.0512x over previous
//
#include <hip/hip_runtime.h>

#define N_NODES 50000
#define N_EDGES 800000

static inline size_t align256(size_t x) { return (x + 255) & ~(size_t)255; }

typedef _Float16 f16x8 __attribute__((ext_vector_type(8)));   // 8 fp16 in 4 VGPRs
typedef float f32x4 __attribute__((ext_vector_type(4)));
typedef float f32x8 __attribute__((ext_vector_type(8)));

// ---------------- CSR build ----------------

// rank[e] = position of edge e within its destination's bucket
__global__ void count_kernel(const int* __restrict__ dst, int* __restrict__ counts,
                             int* __restrict__ rank, int E) {
    int e = blockIdx.x * blockDim.x + threadIdx.x;
    if (e < E) rank[e] = atomicAdd(&counts[dst[e]], 1);
}

__global__ void scan1_kernel(const int* __restrict__ counts, int* __restrict__ row_ptr,
                             int* __restrict__ bsum, int n) {
    __shared__ int sd[1024];
    int i = blockIdx.x * 1024 + threadIdx.x;
    int v = (i < n) ? counts[i] : 0;
    sd[threadIdx.x] = v;
    __syncthreads();
    #pragma unroll
    for (int off = 1; off < 1024; off <<= 1) {
        int t = 0;
        if ((int)threadIdx.x >= off) t = sd[threadIdx.x - off];
        __syncthreads();
        sd[threadIdx.x] += t;
        __syncthreads();
    }
    if (i < n) row_ptr[i + 1] = sd[threadIdx.x];
    if (threadIdx.x == 1023) bsum[blockIdx.x] = sd[1023];
}

// finalize scan (local sum over <=48 block sums), plus dis. 256-thr blocks: i>>10 uniform.
__global__ void scan3_kernel(int* __restrict__ row_ptr, const int* __restrict__ bsum,
                             const int* __restrict__ counts, float* __restrict__ dis, int n) {
    __shared__ int pfx_s;
    if (threadIdx.x == 0) {
        int nb = blockIdx.x >> 2;        // 1024/256
        int p = 0;
        for (int j = 0; j < nb; ++j) p += bsum[j];
        pfx_s = p;
    }
    __syncthreads();
    int i = blockIdx.x * blockDim.x + threadIdx.x;
    if (i < n) {
        row_ptr[i + 1] += pfx_s;
        dis[i] = rsqrtf((float)(counts[i] + 1));
        if (i == 0) row_ptr[0] = 0;
    }
}

// no atomic in dependent chain: slot = row_ptr[dst] + rank
__global__ void fill_kernel(const int* __restrict__ src, const int* __restrict__ dst,
                            const int* __restrict__ rank, const int* __restrict__ row_ptr,
                            int* __restrict__ col, int E) {
    int e = blockIdx.x * blockDim.x + threadIdx.x;
    if (e < E) col[row_ptr[dst[e]] + rank[e]] = src[e];
}

// ---------------- fused prep: pack 4 weights (hi/lo frag order) + xs = fp16(dis*x) ----

__device__ __forceinline__ void pack_dev(const float* __restrict__ W,
                                         _Float16* __restrict__ Ph, _Float16* __restrict__ Pl,
                                         int K, int N, int id) {
    int l = id & 63;
    int f = id >> 6;
    int nf16 = N >> 4;
    int ks = f / nf16, nf = f - ks * nf16;
    int k0 = ks * 32 + (l >> 4) * 8;
    int n  = nf * 16 + (l & 15);
    #pragma unroll
    for (int j = 0; j < 8; ++j) {
        float v = W[(size_t)(k0 + j) * N + n];
        _Float16 hi = (_Float16)v;
        Ph[(size_t)id * 8 + j] = hi;
        Pl[(size_t)id * 8 + j] = (_Float16)(v - (float)hi);
    }
}

__global__ void prep_kernel(const float* __restrict__ W1, _Float16* __restrict__ w1h, _Float16* __restrict__ w1l,
                            const float* __restrict__ W2, _Float16* __restrict__ w2h, _Float16* __restrict__ w2l,
                            const float* __restrict__ W3, _Float16* __restrict__ w3h, _Float16* __restrict__ w3l,
                            const float* __restrict__ W4, _Float16* __restrict__ w4h, _Float16* __restrict__ w4l,
                            const float* __restrict__ x, const float* __restrict__ dis,
                            _Float16* __restrict__ xs) {
    int b = blockIdx.x;
    int tid = threadIdx.x;
    if (b < 16) {                       // W1: 4096 ids
        pack_dev(W1, w1h, w1l, 128, 256, b * 256 + tid);
    } else if (b < 24) {                // W2: 2048 ids
        pack_dev(W2, w2h, w2l, 256, 64, (b - 16) * 256 + tid);
    } else if (b < 32) {                // W3: 2048 ids
        pack_dev(W3, w3h, w3l, 64, 256, (b - 24) * 256 + tid);
    } else if (b < 48) {                // W4: 4096 ids
        pack_dev(W4, w4h, w4l, 256, 128, (b - 32) * 256 + tid);
    } else {                            // xs: N*16 octs of 8
        int q = (b - 48) * 256 + tid;
        if (q < N_NODES * 16) {
            int v = q >> 4, o = q & 15;
            float s = dis[v];
            const float* px = x + (size_t)v * 128 + o * 8;
            float4 t0 = *(const float4*)px;
            float4 t1 = *(const float4*)(px + 4);
            f16x8 h;
            h[0] = (_Float16)(s * t0.x); h[1] = (_Float16)(s * t0.y);
            h[2] = (_Float16)(s * t0.z); h[3] = (_Float16)(s * t0.w);
            h[4] = (_Float16)(s * t1.x); h[5] = (_Float16)(s * t1.y);
            h[6] = (_Float16)(s * t1.z); h[7] = (_Float16)(s * t1.w);
            ((f16x8*)xs)[q] = h;
        }
    }
}

// ---------------- MFMA GEMM (fp16 split x3), A-read-once ----------------
// Block = 256 thr = 4 waves, each wave one 16-row m-frag; block covers 64 rows x ALL N cols.
// acc[NT][4] resident; kt outer, nt inner. A read exactly once; B is L2-hot.
// EPI 0: G16[m,:] = fp16(dis[m]*acc)       EPI 1: Oh/Ol = split(relu(acc+bias))

template <int EPI, int K, int N>
__global__ __launch_bounds__(256) void mfma_gemm(
    const _Float16* __restrict__ Ah, const _Float16* __restrict__ Al,
    const _Float16* __restrict__ Bh, const _Float16* __restrict__ Bl,
    const float* __restrict__ dis, const float* __restrict__ bias,
    _Float16* __restrict__ G16, _Float16* __restrict__ Oh, _Float16* __restrict__ Ol,
    int M) {

    const int NT = N / 64;
    int t = threadIdx.x;
    int w = t >> 6, l = t & 63;
    int m0 = blockIdx.x * 64 + w * 16;
    int lrow = l & 15;
    int lk   = (l >> 4) * 8;

    int r0 = m0 + lrow;
    bool ok0 = r0 < M;

    const _Float16* pAh = Ah + (size_t)r0 * K + lk;
    const _Float16* pAl = Al + (size_t)r0 * K + lk;
    const int nf16 = N >> 4;

    f32x4 acc[NT][4] = {};
    f16x8 z8 = {0, 0, 0, 0, 0, 0, 0, 0};

    #pragma unroll
    for (int kt = 0; kt < K; kt += 32) {
        f16x8 ah = ok0 ? *(const f16x8*)(pAh + kt) : z8;
        f16x8 al = ok0 ? *(const f16x8*)(pAl + kt) : z8;
        const size_t kb = (size_t)(kt >> 5) * nf16 * 512 + (size_t)l * 8;
        #pragma unroll
        for (int nt = 0; nt < NT; ++nt) {
            #pragma unroll
            for (int c = 0; c < 4; ++c) {
                const size_t off = kb + (size_t)(nt * 4 + c) * 512;
                f16x8 bh = *(const f16x8*)(Bh + off);
                f16x8 bl = *(const f16x8*)(Bl + off);
                acc[nt][c] = __builtin_amdgcn_mfma_f32_16x16x32_f16(ah, bh, acc[nt][c], 0, 0, 0);
                acc[nt][c] = __builtin_amdgcn_mfma_f32_16x16x32_f16(al, bh, acc[nt][c], 0, 0, 0);
                acc[nt][c] = __builtin_amdgcn_mfma_f32_16x16x32_f16(ah, bl, acc[nt][c], 0, 0, 0);
            }
        }
    }

    int mb = m0 + (l >> 4) * 4;
    #pragma unroll
    for (int nt = 0; nt < NT; ++nt) {
        float bvals[4];
        if (EPI == 1) {
            #pragma unroll
            for (int c = 0; c < 4; ++c) bvals[c] = bias[nt * 64 + c * 16 + lrow];
        }
        #pragma unroll
        for (int r = 0; r < 4; ++r) {
            int m = mb + r;
            if (m < M) {
                if (EPI == 0) {
                    float s = dis[m];
                    #pragma unroll
                    for (int c = 0; c < 4; ++c) {
                        int n = nt * 64 + c * 16 + lrow;
                        G16[(size_t)m * N + n] = (_Float16)(s * acc[nt][c][r]);
                    }
                } else {
                    #pragma unroll
                    for (int c = 0; c < 4; ++c) {
                        int n = nt * 64 + c * 16 + lrow;
                        float v = fmaxf(acc[nt][c][r] + bvals[c], 0.f);
                        _Float16 hi = (_Float16)v;
                        Oh[(size_t)m * N + n] = hi;
                        Ol[(size_t)m * N + n] = (_Float16)(v - (float)hi);
                    }
                }
            }
        }
    }
}

// ---------------- Aggregation (fp16 gather, f16x8 = 16B/lane, serial per node) ----------
// DQ8 = D/8 lanes per node; block = 256 threads = (256/DQ8) nodes.
// MODE 0: out split(dis[v]*sum)             -> oh/ol fp16   (feeds GEMM)
// MODE 2: out fp16(dis*relu(dis*sum + b))   -> o16          (prescaled for next agg)
// MODE 3: out fp32(dis*sum + b)             -> outf         (final layer)

template <int MODE, int DQ8>
__global__ __launch_bounds__(256) void agg8(
    const _Float16* __restrict__ g, const int* __restrict__ row_ptr,
    const int* __restrict__ col, const float* __restrict__ dis,
    const float* __restrict__ bias, float* __restrict__ outf,
    _Float16* __restrict__ o16, _Float16* __restrict__ oh, _Float16* __restrict__ ol) {
    const int NPB = 256 / DQ8;
    int t = threadIdx.x;
    int nl = t / DQ8, c = t % DQ8;
    int v = blockIdx.x * NPB + nl;
    if (v >= N_NODES) return;
    const f16x8* g8 = (const f16x8*)g;
    size_t rowo = (size_t)v * DQ8 + c;

    f32x8 sum = __builtin_convertvector(g8[rowo], f32x8);   // self-loop term

    int s = row_ptr[v], e = row_ptr[v + 1];
    int i = s;
    for (; i + 4 <= e; i += 4) {
        int u0 = col[i], u1 = col[i + 1], u2 = col[i + 2], u3 = col[i + 3];
        f32x8 f0 = __builtin_convertvector(g8[(size_t)u0 * DQ8 + c], f32x8);
        f32x8 f1 = __builtin_convertvector(g8[(size_t)u1 * DQ8 + c], f32x8);
        f32x8 f2 = __builtin_convertvector(g8[(size_t)u2 * DQ8 + c], f32x8);
        f32x8 f3 = __builtin_convertvector(g8[(size_t)u3 * DQ8 + c], f32x8);
        sum += (f0 + f1) + (f2 + f3);
    }
    for (; i < e; ++i)
        sum += __builtin_convertvector(g8[(size_t)col[i] * DQ8 + c], f32x8);

    float dv = dis[v];
    if (MODE == 0) {
        f16x8 h, lo;
        #pragma unroll
        for (int j = 0; j < 8; ++j) {
            float r = dv * sum[j];
            h[j]  = (_Float16)r;
            lo[j] = (_Float16)(r - (float)h[j]);
        }
        ((f16x8*)oh)[rowo] = h;
        ((f16x8*)ol)[rowo] = lo;
    } else {
        f32x8 bv = ((const f32x8*)bias)[c];
        if (MODE == 2) {
            f16x8 h;
            #pragma unroll
            for (int j = 0; j < 8; ++j) {
                float r = fmaxf(dv * sum[j] + bv[j], 0.f) * dv;
                h[j] = (_Float16)r;
            }
            ((f16x8*)o16)[rowo] = h;
        } else {
            f32x8 r;
            #pragma unroll
            for (int j = 0; j < 8; ++j) r[j] = dv * sum[j] + bv[j];
            ((f32x8*)outf)[rowo] = r;
        }
    }
}

// ---------------- launch ----------------

extern "C" void kernel_launch(void* const* d_in, const int* in_sizes, int n_in,
                              void* d_out, int out_size, void* d_ws, size_t ws_size,
                              hipStream_t stream) {
    const int N = N_NODES, E = N_EDGES;

    const float* x   = (const float*)d_in[0];
    const int*   ei  = (const int*)d_in[1];
    const int*   src = ei;
    const int*   dst = ei + E;
    const float* W1 = (const float*)d_in[2];  const float* b1 = (const float*)d_in[3];
    const float* W2 = (const float*)d_in[4];  const float* b2 = (const float*)d_in[5];
    const float* W3 = (const float*)d_in[6];  const float* b3 = (const float*)d_in[7];
    const float* W4 = (const float*)d_in[8];  const float* b4 = (const float*)d_in[9];
    float* out = (float*)d_out;

    // workspace carve-up
    char* w = (char*)d_ws;
    int*   counts  = (int*)w;    w += align256((size_t)N * 4);
    int*   row_ptr = (int*)w;    w += align256((size_t)(N + 1) * 4);
    float* dis     = (float*)w;  w += align256((size_t)N * 4);
    int*   bsum    = (int*)w;    w += align256((size_t)64 * 4);
    int*   rank    = (int*)w;    w += align256((size_t)E * 4);
    int*   col     = (int*)w;    w += align256((size_t)E * 4);
    _Float16* w1h = (_Float16*)w; w += align256(32768 * 2);
    _Float16* w1l = (_Float16*)w; w += align256(32768 * 2);
    _Float16* w2h = (_Float16*)w; w += align256(16384 * 2);
    _Float16* w2l = (_Float16*)w; w += align256(16384 * 2);
    _Float16* w3h = (_Float16*)w; w += align256(16384 * 2);
    _Float16* w3l = (_Float16*)w; w += align256(16384 * 2);
    _Float16* w4h = (_Float16*)w; w += align256(32768 * 2);
    _Float16* w4l = (_Float16*)w; w += align256(32768 * 2);
    // arenas (aliased across phases), all fp16
    char* A1 = w;  w += align256((size_t)N * 128 * 2);   // xs | t3h+t3l
    char* A2 = w;  w += align256((size_t)N * 128 * 2);   // t1h | g2+h2s
    char* A3 = w;  w += align256((size_t)N * 128 * 2);   // t1l | gg4
    char* A4 = w;  w += align256((size_t)N * 256 * 2);   // h1h | h3h
    char* A5 = w;  w += align256((size_t)N * 256 * 2);   // h1l | h3l

    _Float16* xs  = (_Float16*)A1;
    _Float16* t1h = (_Float16*)A2;
    _Float16* t1l = (_Float16*)A3;
    _Float16* h1h = (_Float16*)A4;
    _Float16* h1l = (_Float16*)A5;
    _Float16* g2  = (_Float16*)A2;
    _Float16* h2s = (_Float16*)(A2 + (size_t)N * 64 * 2);
    _Float16* t3h = (_Float16*)A1;
    _Float16* t3l = (_Float16*)(A1 + (size_t)N * 64 * 2);
    _Float16* h3h = (_Float16*)A4;
    _Float16* h3l = (_Float16*)A5;
    _Float16* gg4 = (_Float16*)A3;

    // ---- CSR build (5 dispatches) ----
    const int nb = (N + 1023) / 1024;
    hipMemsetAsync(counts, 0, (size_t)N * 4, stream);
    count_kernel<<<(E + 255) / 256, 256, 0, stream>>>(dst, counts, rank, E);
    scan1_kernel<<<nb, 1024, 0, stream>>>(counts, row_ptr, bsum, N);
    scan3_kernel<<<(N + 255) / 256, 256, 0, stream>>>(row_ptr, bsum, counts, dis, N);
    fill_kernel<<<(E + 255) / 256, 256, 0, stream>>>(src, dst, rank, row_ptr, col, E);

    // ---- fused prep: 4x pack_w + xs (1 dispatch) ----
    prep_kernel<<<48 + (N * 16 + 255) / 256, 256, 0, stream>>>(
        W1, w1h, w1l, W2, w2h, w2l, W3, w3h, w3l, W4, w4h, w4l, x, dis, xs);

    const int gx = (N + 63) / 64;   // 782 blocks, 64 rows each

    // ---- layer 1 (agg-first): t1 = Âs xs ; h1 = relu(t1 @ W1 + b1) ----
    agg8<0, 16><<<(N + 15) / 16, 256, 0, stream>>>(xs, row_ptr, col, dis, nullptr,
                                                   nullptr, nullptr, t1h, t1l);
    mfma_gemm<1, 128, 256><<<gx, 256, 0, stream>>>(t1h, t1l, w1h, w1l, dis, b1,
                                                   nullptr, h1h, h1l, N);

    // ---- layer 2 (agg-after): g2 = fp16(dis*(h1 @ W2)) ; h2s = fp16(dis*relu(agg + b2)) ----
    mfma_gemm<0, 256, 64><<<gx, 256, 0, stream>>>(h1h, h1l, w2h, w2l, dis, b2,
                                                  g2, nullptr, nullptr, N);
    agg8<2, 8><<<(N + 31) / 32, 256, 0, stream>>>(g2, row_ptr, col, dis, b2,
                                                  nullptr, h2s, nullptr, nullptr);

    // ---- layer 3 (agg-first): t3 = Âs h2s ; h3 = relu(t3 @ W3 + b3) ----
    agg8<0, 8><<<(N + 31) / 32, 256, 0, stream>>>(h2s, row_ptr, col, dis, nullptr,
                                                  nullptr, nullptr, t3h, t3l);
    mfma_gemm<1, 64, 256><<<gx, 256, 0, stream>>>(t3h, t3l, w3h, w3l, dis, b3,
                                                  nullptr, h3h, h3l, N);

    // ---- layer 4 (agg-after): gg4 = fp16(dis*(h3 @ W4)) ; out = agg + b4 ----
    mfma_gemm<0, 256, 128><<<gx, 256, 0, stream>>>(h3h, h3l, w4h, w4l, dis, b4,
                                                   gg4, nullptr, nullptr, N);
    agg8<3, 16><<<(N + 15) / 16, 256, 0, stream>>>(gg4, row_ptr, col, dis, b4,
                                                   out, nullptr, nullptr, nullptr);
}

// Round 9
// 247.700 us; speedup vs baseline: 1.3191x; 1.2549x over previous
//
#include <hip/hip_runtime.h>

#define N_NODES 50000
#define N_EDGES 800000

static inline size_t align256(size_t x) { return (x + 255) & ~(size_t)255; }

typedef _Float16 f16x8 __attribute__((ext_vector_type(8)));   // 8 fp16 in 4 VGPRs
typedef float f32x4 __attribute__((ext_vector_type(4)));
typedef float f32x8 __attribute__((ext_vector_type(8)));

// ---------------- CSR build ----------------

// rank[e] = position of edge e within its destination's bucket
__global__ void count_kernel(const int* __restrict__ dst, int* __restrict__ counts,
                             int* __restrict__ rank, int E) {
    int e = blockIdx.x * blockDim.x + threadIdx.x;
    if (e < E) rank[e] = atomicAdd(&counts[dst[e]], 1);
}

__global__ void scan1_kernel(const int* __restrict__ counts, int* __restrict__ row_ptr,
                             int* __restrict__ bsum, int n) {
    __shared__ int sd[1024];
    int i = blockIdx.x * 1024 + threadIdx.x;
    int v = (i < n) ? counts[i] : 0;
    sd[threadIdx.x] = v;
    __syncthreads();
    #pragma unroll
    for (int off = 1; off < 1024; off <<= 1) {
        int t = 0;
        if ((int)threadIdx.x >= off) t = sd[threadIdx.x - off];
        __syncthreads();
        sd[threadIdx.x] += t;
        __syncthreads();
    }
    if (i < n) row_ptr[i + 1] = sd[threadIdx.x];
    if (threadIdx.x == 1023) bsum[blockIdx.x] = sd[1023];
}

// finalize scan (local sum over <=48 block sums), plus dis. 256-thr blocks: i>>10 uniform.
__global__ void scan3_kernel(int* __restrict__ row_ptr, const int* __restrict__ bsum,
                             const int* __restrict__ counts, float* __restrict__ dis, int n) {
    __shared__ int pfx_s;
    if (threadIdx.x == 0) {
        int nb = blockIdx.x >> 2;        // 1024/256
        int p = 0;
        for (int j = 0; j < nb; ++j) p += bsum[j];
        pfx_s = p;
    }
    __syncthreads();
    int i = blockIdx.x * blockDim.x + threadIdx.x;
    if (i < n) {
        row_ptr[i + 1] += pfx_s;
        dis[i] = rsqrtf((float)(counts[i] + 1));
        if (i == 0) row_ptr[0] = 0;
    }
}

// no atomic in dependent chain: slot = row_ptr[dst] + rank
__global__ void fill_kernel(const int* __restrict__ src, const int* __restrict__ dst,
                            const int* __restrict__ rank, const int* __restrict__ row_ptr,
                            int* __restrict__ col, int E) {
    int e = blockIdx.x * blockDim.x + threadIdx.x;
    if (e < E) col[row_ptr[dst[e]] + rank[e]] = src[e];
}

// ---------------- fused prep: pack 4 weights (hi/lo frag order) + xs = fp16(dis*x) ----

__device__ __forceinline__ void pack_dev(const float* __restrict__ W,
                                         _Float16* __restrict__ Ph, _Float16* __restrict__ Pl,
                                         int K, int N, int id) {
    int l = id & 63;
    int f = id >> 6;
    int nf16 = N >> 4;
    int ks = f / nf16, nf = f - ks * nf16;
    int k0 = ks * 32 + (l >> 4) * 8;
    int n  = nf * 16 + (l & 15);
    #pragma unroll
    for (int j = 0; j < 8; ++j) {
        float v = W[(size_t)(k0 + j) * N + n];
        _Float16 hi = (_Float16)v;
        Ph[(size_t)id * 8 + j] = hi;
        Pl[(size_t)id * 8 + j] = (_Float16)(v - (float)hi);
    }
}

__global__ void prep_kernel(const float* __restrict__ W1, _Float16* __restrict__ w1h, _Float16* __restrict__ w1l,
                            const float* __restrict__ W2, _Float16* __restrict__ w2h, _Float16* __restrict__ w2l,
                            const float* __restrict__ W3, _Float16* __restrict__ w3h, _Float16* __restrict__ w3l,
                            const float* __restrict__ W4, _Float16* __restrict__ w4h, _Float16* __restrict__ w4l,
                            const float* __restrict__ x, const float* __restrict__ dis,
                            _Float16* __restrict__ xs) {
    int b = blockIdx.x;
    int tid = threadIdx.x;
    if (b < 16) {                       // W1: 4096 ids
        pack_dev(W1, w1h, w1l, 128, 256, b * 256 + tid);
    } else if (b < 24) {                // W2: 2048 ids
        pack_dev(W2, w2h, w2l, 256, 64, (b - 16) * 256 + tid);
    } else if (b < 32) {                // W3: 2048 ids
        pack_dev(W3, w3h, w3l, 64, 256, (b - 24) * 256 + tid);
    } else if (b < 48) {                // W4: 4096 ids
        pack_dev(W4, w4h, w4l, 256, 128, (b - 32) * 256 + tid);
    } else {                            // xs: N*16 octs of 8
        int q = (b - 48) * 256 + tid;
        if (q < N_NODES * 16) {
            int v = q >> 4, o = q & 15;
            float s = dis[v];
            const float* px = x + (size_t)v * 128 + o * 8;
            float4 t0 = *(const float4*)px;
            float4 t1 = *(const float4*)(px + 4);
            f16x8 h;
            h[0] = (_Float16)(s * t0.x); h[1] = (_Float16)(s * t0.y);
            h[2] = (_Float16)(s * t0.z); h[3] = (_Float16)(s * t0.w);
            h[4] = (_Float16)(s * t1.x); h[5] = (_Float16)(s * t1.y);
            h[6] = (_Float16)(s * t1.z); h[7] = (_Float16)(s * t1.w);
            ((f16x8*)xs)[q] = h;
        }
    }
}

// ---------------- MFMA GEMM (fp16 split x3), LDS-staged B, double-buffered ----------------
// Block = 256 thr = 4 waves; each wave 2 m-frags (32 rows) -> block = 128 rows x ALL N cols.
// Per k-slice (32), B hi/lo staged to LDS (frag order, contiguous); 1 barrier per slice.
// Each LDS bh/bl pair feeds 6 MFMAs (2 frags x 3 split passes).
// EPI 0: G16[m,:] = fp16(dis[m]*acc)       EPI 1: Oh/Ol = split(relu(acc+bias))

template <int EPI, int K, int N>
__global__ __launch_bounds__(256) void mfma_gemm(
    const _Float16* __restrict__ Ah, const _Float16* __restrict__ Al,
    const _Float16* __restrict__ Bh, const _Float16* __restrict__ Bl,
    const float* __restrict__ dis, const float* __restrict__ bias,
    _Float16* __restrict__ G16, _Float16* __restrict__ Oh, _Float16* __restrict__ Ol,
    int M) {

    const int NT = N / 64;          // 64-col sweeps per wave
    const int NF = N / 16;          // frags per k-slice
    const int KT = K / 32;          // k-slices
    const int CP = NF / 4;          // f16x8 copies per thread per half-slice

    __shared__ _Float16 lds[2][2][NF * 512];   // [buf][hi/lo][frag-ordered slice]

    int t = threadIdx.x;
    int w = t >> 6, l = t & 63;
    int m0 = blockIdx.x * 128 + w * 32;
    int lrow = l & 15;
    int lk   = (l >> 4) * 8;

    int r0 = m0 + lrow, r1 = m0 + 16 + lrow;
    bool ok0 = r0 < M, ok1 = r1 < M;

    const _Float16* pAh0 = Ah + (size_t)r0 * K + lk;
    const _Float16* pAl0 = Al + (size_t)r0 * K + lk;
    const _Float16* pAh1 = Ah + (size_t)r1 * K + lk;
    const _Float16* pAl1 = Al + (size_t)r1 * K + lk;

    const f16x8* Bh8 = (const f16x8*)Bh;
    const f16x8* Bl8 = (const f16x8*)Bl;

    f32x4 acc[2][NT][4] = {};
    f16x8 z8 = {0, 0, 0, 0, 0, 0, 0, 0};

    // B-slice staging regs (reused each slice) + A frags (parity-double-buffered)
    f16x8 ph[CP], pl[CP];
    f16x8 pa[2][4];

    #pragma unroll
    for (int j = 0; j < CP; ++j) {
        ph[j] = Bh8[j * 256 + t];
        pl[j] = Bl8[j * 256 + t];
    }
    pa[0][0] = ok0 ? *(const f16x8*)(pAh0) : z8;
    pa[0][1] = ok0 ? *(const f16x8*)(pAl0) : z8;
    pa[0][2] = ok1 ? *(const f16x8*)(pAh1) : z8;
    pa[0][3] = ok1 ? *(const f16x8*)(pAl1) : z8;

    #pragma unroll
    for (int ks = 0; ks < KT; ++ks) {
        const int cur = ks & 1;
        // write staged B slice into LDS buffer `cur`
        f16x8* dh = (f16x8*)lds[cur][0];
        f16x8* dl = (f16x8*)lds[cur][1];
        #pragma unroll
        for (int j = 0; j < CP; ++j) {
            dh[j * 256 + t] = ph[j];
            dl[j * 256 + t] = pl[j];
        }
        // prefetch next slice (B + A) — flies during barrier + compute
        if (ks + 1 < KT) {
            const size_t nb = (size_t)(ks + 1) * NF * 64;
            #pragma unroll
            for (int j = 0; j < CP; ++j) {
                ph[j] = Bh8[nb + j * 256 + t];
                pl[j] = Bl8[nb + j * 256 + t];
            }
            const int ko = (ks + 1) * 32;
            pa[(ks + 1) & 1][0] = ok0 ? *(const f16x8*)(pAh0 + ko) : z8;
            pa[(ks + 1) & 1][1] = ok0 ? *(const f16x8*)(pAl0 + ko) : z8;
            pa[(ks + 1) & 1][2] = ok1 ? *(const f16x8*)(pAh1 + ko) : z8;
            pa[(ks + 1) & 1][3] = ok1 ? *(const f16x8*)(pAl1 + ko) : z8;
        }
        __syncthreads();

        const f16x8 ah0 = pa[cur][0], al0 = pa[cur][1];
        const f16x8 ah1 = pa[cur][2], al1 = pa[cur][3];
        const f16x8* lbh = (const f16x8*)lds[cur][0];
        const f16x8* lbl = (const f16x8*)lds[cur][1];

        #pragma unroll
        for (int nt = 0; nt < NT; ++nt) {
            #pragma unroll
            for (int c = 0; c < 4; ++c) {
                const int nf = nt * 4 + c;
                f16x8 bh = lbh[nf * 64 + l];
                f16x8 bl = lbl[nf * 64 + l];
                acc[0][nt][c] = __builtin_amdgcn_mfma_f32_16x16x32_f16(ah0, bh, acc[0][nt][c], 0, 0, 0);
                acc[0][nt][c] = __builtin_amdgcn_mfma_f32_16x16x32_f16(al0, bh, acc[0][nt][c], 0, 0, 0);
                acc[0][nt][c] = __builtin_amdgcn_mfma_f32_16x16x32_f16(ah0, bl, acc[0][nt][c], 0, 0, 0);
                acc[1][nt][c] = __builtin_amdgcn_mfma_f32_16x16x32_f16(ah1, bh, acc[1][nt][c], 0, 0, 0);
                acc[1][nt][c] = __builtin_amdgcn_mfma_f32_16x16x32_f16(al1, bh, acc[1][nt][c], 0, 0, 0);
                acc[1][nt][c] = __builtin_amdgcn_mfma_f32_16x16x32_f16(ah1, bl, acc[1][nt][c], 0, 0, 0);
            }
        }
    }

    #pragma unroll
    for (int rf = 0; rf < 2; ++rf) {
        int mb = m0 + rf * 16 + (l >> 4) * 4;
        #pragma unroll
        for (int nt = 0; nt < NT; ++nt) {
            float bvals[4];
            if (EPI == 1) {
                #pragma unroll
                for (int c = 0; c < 4; ++c) bvals[c] = bias[nt * 64 + c * 16 + lrow];
            }
            #pragma unroll
            for (int r = 0; r < 4; ++r) {
                int m = mb + r;
                if (m < M) {
                    if (EPI == 0) {
                        float s = dis[m];
                        #pragma unroll
                        for (int c = 0; c < 4; ++c) {
                            int n = nt * 64 + c * 16 + lrow;
                            G16[(size_t)m * N + n] = (_Float16)(s * acc[rf][nt][c][r]);
                        }
                    } else {
                        #pragma unroll
                        for (int c = 0; c < 4; ++c) {
                            int n = nt * 64 + c * 16 + lrow;
                            float v = fmaxf(acc[rf][nt][c][r] + bvals[c], 0.f);
                            _Float16 hi = (_Float16)v;
                            Oh[(size_t)m * N + n] = hi;
                            Ol[(size_t)m * N + n] = (_Float16)(v - (float)hi);
                        }
                    }
                }
            }
        }
    }
}

// ---------------- Aggregation (fp16 gather, f16x8 = 16B/lane, serial per node) ----------
// DQ8 = D/8 lanes per node; block = 256 threads = (256/DQ8) nodes.
// MODE 0: out split(dis[v]*sum)             -> oh/ol fp16   (feeds GEMM)
// MODE 2: out fp16(dis*relu(dis*sum + b))   -> o16          (prescaled for next agg)
// MODE 3: out fp32(dis*sum + b)             -> outf         (final layer)

template <int MODE, int DQ8>
__global__ __launch_bounds__(256) void agg8(
    const _Float16* __restrict__ g, const int* __restrict__ row_ptr,
    const int* __restrict__ col, const float* __restrict__ dis,
    const float* __restrict__ bias, float* __restrict__ outf,
    _Float16* __restrict__ o16, _Float16* __restrict__ oh, _Float16* __restrict__ ol) {
    const int NPB = 256 / DQ8;
    int t = threadIdx.x;
    int nl = t / DQ8, c = t % DQ8;
    int v = blockIdx.x * NPB + nl;
    if (v >= N_NODES) return;
    const f16x8* g8 = (const f16x8*)g;
    size_t rowo = (size_t)v * DQ8 + c;

    f32x8 sum = __builtin_convertvector(g8[rowo], f32x8);   // self-loop term

    int s = row_ptr[v], e = row_ptr[v + 1];
    int i = s;
    for (; i + 4 <= e; i += 4) {
        int u0 = col[i], u1 = col[i + 1], u2 = col[i + 2], u3 = col[i + 3];
        f32x8 f0 = __builtin_convertvector(g8[(size_t)u0 * DQ8 + c], f32x8);
        f32x8 f1 = __builtin_convertvector(g8[(size_t)u1 * DQ8 + c], f32x8);
        f32x8 f2 = __builtin_convertvector(g8[(size_t)u2 * DQ8 + c], f32x8);
        f32x8 f3 = __builtin_convertvector(g8[(size_t)u3 * DQ8 + c], f32x8);
        sum += (f0 + f1) + (f2 + f3);
    }
    for (; i < e; ++i)
        sum += __builtin_convertvector(g8[(size_t)col[i] * DQ8 + c], f32x8);

    float dv = dis[v];
    if (MODE == 0) {
        f16x8 h, lo;
        #pragma unroll
        for (int j = 0; j < 8; ++j) {
            float r = dv * sum[j];
            h[j]  = (_Float16)r;
            lo[j] = (_Float16)(r - (float)h[j]);
        }
        ((f16x8*)oh)[rowo] = h;
        ((f16x8*)ol)[rowo] = lo;
    } else {
        f32x8 bv = ((const f32x8*)bias)[c];
        if (MODE == 2) {
            f16x8 h;
            #pragma unroll
            for (int j = 0; j < 8; ++j) {
                float r = fmaxf(dv * sum[j] + bv[j], 0.f) * dv;
                h[j] = (_Float16)r;
            }
            ((f16x8*)o16)[rowo] = h;
        } else {
            f32x8 r;
            #pragma unroll
            for (int j = 0; j < 8; ++j) r[j] = dv * sum[j] + bv[j];
            ((f32x8*)outf)[rowo] = r;
        }
    }
}

// ---------------- launch ----------------

extern "C" void kernel_launch(void* const* d_in, const int* in_sizes, int n_in,
                              void* d_out, int out_size, void* d_ws, size_t ws_size,
                              hipStream_t stream) {
    const int N = N_NODES, E = N_EDGES;

    const float* x   = (const float*)d_in[0];
    const int*   ei  = (const int*)d_in[1];
    const int*   src = ei;
    const int*   dst = ei + E;
    const float* W1 = (const float*)d_in[2];  const float* b1 = (const float*)d_in[3];
    const float* W2 = (const float*)d_in[4];  const float* b2 = (const float*)d_in[5];
    const float* W3 = (const float*)d_in[6];  const float* b3 = (const float*)d_in[7];
    const float* W4 = (const float*)d_in[8];  const float* b4 = (const float*)d_in[9];
    float* out = (float*)d_out;

    // workspace carve-up
    char* w = (char*)d_ws;
    int*   counts  = (int*)w;    w += align256((size_t)N * 4);
    int*   row_ptr = (int*)w;    w += align256((size_t)(N + 1) * 4);
    float* dis     = (float*)w;  w += align256((size_t)N * 4);
    int*   bsum    = (int*)w;    w += align256((size_t)64 * 4);
    int*   rank    = (int*)w;    w += align256((size_t)E * 4);
    int*   col     = (int*)w;    w += align256((size_t)E * 4);
    _Float16* w1h = (_Float16*)w; w += align256(32768 * 2);
    _Float16* w1l = (_Float16*)w; w += align256(32768 * 2);
    _Float16* w2h = (_Float16*)w; w += align256(16384 * 2);
    _Float16* w2l = (_Float16*)w; w += align256(16384 * 2);
    _Float16* w3h = (_Float16*)w; w += align256(16384 * 2);
    _Float16* w3l = (_Float16*)w; w += align256(16384 * 2);
    _Float16* w4h = (_Float16*)w; w += align256(32768 * 2);
    _Float16* w4l = (_Float16*)w; w += align256(32768 * 2);
    // arenas (aliased across phases), all fp16
    char* A1 = w;  w += align256((size_t)N * 128 * 2);   // xs | t3h+t3l
    char* A2 = w;  w += align256((size_t)N * 128 * 2);   // t1h | g2+h2s
    char* A3 = w;  w += align256((size_t)N * 128 * 2);   // t1l | gg4
    char* A4 = w;  w += align256((size_t)N * 256 * 2);   // h1h | h3h
    char* A5 = w;  w += align256((size_t)N * 256 * 2);   // h1l | h3l

    _Float16* xs  = (_Float16*)A1;
    _Float16* t1h = (_Float16*)A2;
    _Float16* t1l = (_Float16*)A3;
    _Float16* h1h = (_Float16*)A4;
    _Float16* h1l = (_Float16*)A5;
    _Float16* g2  = (_Float16*)A2;
    _Float16* h2s = (_Float16*)(A2 + (size_t)N * 64 * 2);
    _Float16* t3h = (_Float16*)A1;
    _Float16* t3l = (_Float16*)(A1 + (size_t)N * 64 * 2);
    _Float16* h3h = (_Float16*)A4;
    _Float16* h3l = (_Float16*)A5;
    _Float16* gg4 = (_Float16*)A3;

    // ---- CSR build ----
    const int nb = (N + 1023) / 1024;
    hipMemsetAsync(counts, 0, (size_t)N * 4, stream);
    count_kernel<<<(E + 255) / 256, 256, 0, stream>>>(dst, counts, rank, E);
    scan1_kernel<<<nb, 1024, 0, stream>>>(counts, row_ptr, bsum, N);
    scan3_kernel<<<(N + 255) / 256, 256, 0, stream>>>(row_ptr, bsum, counts, dis, N);
    fill_kernel<<<(E + 255) / 256, 256, 0, stream>>>(src, dst, rank, row_ptr, col, E);

    // ---- fused prep: 4x pack_w + xs (1 dispatch) ----
    prep_kernel<<<48 + (N * 16 + 255) / 256, 256, 0, stream>>>(
        W1, w1h, w1l, W2, w2h, w2l, W3, w3h, w3l, W4, w4h, w4l, x, dis, xs);

    const int gx = (N + 127) / 128;   // 391 blocks, 128 rows each

    // ---- layer 1 (agg-first): t1 = Âs xs ; h1 = relu(t1 @ W1 + b1) ----
    agg8<0, 16><<<(N + 15) / 16, 256, 0, stream>>>(xs, row_ptr, col, dis, nullptr,
                                                   nullptr, nullptr, t1h, t1l);
    mfma_gemm<1, 128, 256><<<gx, 256, 0, stream>>>(t1h, t1l, w1h, w1l, dis, b1,
                                                   nullptr, h1h, h1l, N);

    // ---- layer 2 (agg-after): g2 = fp16(dis*(h1 @ W2)) ; h2s = fp16(dis*relu(agg + b2)) ----
    mfma_gemm<0, 256, 64><<<gx, 256, 0, stream>>>(h1h, h1l, w2h, w2l, dis, b2,
                                                  g2, nullptr, nullptr, N);
    agg8<2, 8><<<(N + 31) / 32, 256, 0, stream>>>(g2, row_ptr, col, dis, b2,
                                                  nullptr, h2s, nullptr, nullptr);

    // ---- layer 3 (agg-first): t3 = Âs h2s ; h3 = relu(t3 @ W3 + b3) ----
    agg8<0, 8><<<(N + 31) / 32, 256, 0, stream>>>(h2s, row_ptr, col, dis, nullptr,
                                                  nullptr, nullptr, t3h, t3l);
    mfma_gemm<1, 64, 256><<<gx, 256, 0, stream>>>(t3h, t3l, w3h, w3l, dis, b3,
                                                  nullptr, h3h, h3l, N);

    // ---- layer 4 (agg-after): gg4 = fp16(dis*(h3 @ W4)) ; out = agg + b4 ----
    mfma_gemm<0, 256, 128><<<gx, 256, 0, stream>>>(h3h, h3l, w4h, w4l, dis, b4,
                                                   gg4, nullptr, nullptr, N);
    agg8<3, 16><<<(N + 15) / 16, 256, 0, stream>>>(gg4, row_ptr, col, dis, b4,
                                                   out, nullptr, nullptr, nullptr);
}